// Round 1
// baseline (287.318 us; speedup 1.0000x reference)
//
#include <hip/hip_runtime.h>
#include <hip/hip_bf16.h>

using bf = __bf16;
typedef __attribute__((ext_vector_type(8))) __bf16 bf16x8;
typedef __attribute__((ext_vector_type(4))) float f32x4;

#define MFMA(a, b, c) __builtin_amdgcn_mfma_f32_16x16x32_bf16((a), (b), (c), 0, 0, 0)
#define GLL16(g, s)                                                         \
    __builtin_amdgcn_global_load_lds(                                       \
        (const __attribute__((address_space(1))) void*)(g),                 \
        (__attribute__((address_space(3))) void*)(s), 16, 0, 0)

// ---------------- fp32 -> bf16 converts (merged, 8 elems/thread) ----------------
static __device__ __forceinline__ void cvt_one(const float* __restrict__ s,
                                               bf* __restrict__ d, int i)
{
    const f32x4 a = ((const f32x4*)s)[2 * i];
    const f32x4 b = ((const f32x4*)s)[2 * i + 1];
    bf16x8 r;
#pragma unroll
    for (int k = 0; k < 4; ++k) { r[k] = (bf)a[k]; r[4 + k] = (bf)b[k]; }
    ((bf16x8*)d)[i] = r;
}

__global__ __launch_bounds__(256) void cvt2(const float* __restrict__ s1, bf* __restrict__ d1, int n1,
                                            const float* __restrict__ s2, bf* __restrict__ d2, int n2)
{
    int i = blockIdx.x * 256 + threadIdx.x;
    if (i < n1) { cvt_one(s1, d1, i); return; }
    i -= n1;
    if (i < n2) cvt_one(s2, d2, i);
}

__global__ __launch_bounds__(256) void cvt3(const float* __restrict__ s1, bf* __restrict__ d1, int n1,
                                            const float* __restrict__ s2, bf* __restrict__ d2, int n2,
                                            const float* __restrict__ s3, bf* __restrict__ d3, int n3)
{
    int i = blockIdx.x * 256 + threadIdx.x;
    if (i < n1) { cvt_one(s1, d1, i); return; }
    i -= n1;
    if (i < n2) { cvt_one(s2, d2, i); return; }
    i -= n2;
    if (i < n3) cvt_one(s3, d3, i);
}

// ---------------- m97-style 128x128 bf16 GEMM (kept for output projection) ----------------
// EPI 1: bias + fp32 residual, fp32 out row-major
template <int EPI, int GH, int LGR>
__global__ __launch_bounds__(256) void gemm128(
    const bf* __restrict__ A, const bf* __restrict__ W,
    const float* __restrict__ bias, const float* __restrict__ res,
    void* __restrict__ Cout, int M, int N, int K)
{
    __shared__ __attribute__((aligned(16))) bf As[128 * 32];
    __shared__ __attribute__((aligned(16))) bf Bs[128 * 32];

    const int lane = threadIdx.x & 63;
    const int wave = threadIdx.x >> 6;
    const int lm = lane & 15;
    const int quad = lane >> 4;
    const int row0 = blockIdx.x * 128, col0 = blockIdx.y * 128;
    const int wrow = (wave >> 1) * 64, wcol = (wave & 1) * 64;

    const int sr = lane >> 2;
    const int sc = (lane & 3) * 8;
    const bf* Ag = A + (size_t)(row0 + wave * 32 + sr) * K + sc;
    const bf* Wg = W + (size_t)(col0 + wave * 32 + sr) * K + sc;
    bf* AsW = As + wave * 1024;
    bf* BsW = Bs + wave * 1024;

    f32x4 acc[4][4] = {};

    for (int k0 = 0; k0 < K; k0 += 32) {
        GLL16(Ag + k0, AsW);
        GLL16(Ag + (size_t)16 * K + k0, AsW + 512);
        GLL16(Wg + k0, BsW);
        GLL16(Wg + (size_t)16 * K + k0, BsW + 512);
        __syncthreads();

        bf16x8 a[4], b[4];
#pragma unroll
        for (int i = 0; i < 4; ++i)
            a[i] = *(const bf16x8*)(As + (wrow + i * 16 + lm) * 32 + quad * 8);
#pragma unroll
        for (int j = 0; j < 4; ++j)
            b[j] = *(const bf16x8*)(Bs + (wcol + j * 16 + lm) * 32 + quad * 8);
#pragma unroll
        for (int i = 0; i < 4; ++i)
#pragma unroll
            for (int j = 0; j < 4; ++j)
                acc[i][j] = MFMA(a[i], b[j], acc[i][j]);
        __syncthreads();
    }

    float bv[4];
#pragma unroll
    for (int j = 0; j < 4; ++j) bv[j] = bias[col0 + wcol + j * 16 + lm];

    if (EPI == 0) {
        bf* C = (bf*)Cout;
        const int g = (col0 + wcol) >> 6;
#pragma unroll
        for (int i = 0; i < 4; ++i) {
#pragma unroll
            for (int rg = 0; rg < 4; ++rg) {
                float v[4];
                float ss = 0.f;
#pragma unroll
                for (int j = 0; j < 4; ++j) {
                    const float x = acc[i][j][rg] + bv[j];
                    v[j] = x;
                    ss += x * x;
                }
                ss += __shfl_xor(ss, 1, 64);
                ss += __shfl_xor(ss, 2, 64);
                ss += __shfl_xor(ss, 4, 64);
                ss += __shfl_xor(ss, 8, 64);
                const float inv = 1.0f / fmaxf(sqrtf(ss), 1e-12f);
                const int row = row0 + wrow + i * 16 + quad * 4 + rg;
                const int bt = row >> LGR;
                const int rl = row & ((1 << LGR) - 1);
                bf* Cr = C + (((size_t)(bt * GH + g) << LGR) + rl) * 64;
#pragma unroll
                for (int j = 0; j < 4; ++j)
                    Cr[j * 16 + lm] = (bf)(v[j] * inv);
            }
        }
    } else {
        float* C = (float*)Cout;
#pragma unroll
        for (int i = 0; i < 4; ++i) {
#pragma unroll
            for (int rg = 0; rg < 4; ++rg) {
                const int row = row0 + wrow + i * 16 + quad * 4 + rg;
#pragma unroll
                for (int j = 0; j < 4; ++j) {
                    const size_t idx = (size_t)row * N + col0 + wcol + j * 16 + lm;
                    C[idx] = acc[i][j][rg] + bv[j] + res[idx];
                }
            }
        }
    }
}

// ---------------- 256x256 8-phase bf16 GEMM (T2 swizzle + T3/T4 counted vmcnt + T5 setprio) ----
// C = A @ W^T, epilogue: bias + per-64-col-head L2-norm, bf16 head-major out (same as gemm128 EPI0).
// 512 thr = 8 waves (2M x 4N); wave owns 128x64. BK=64, double-buffered LDS = 128 KiB (dynamic).
// LDS layout per (buf, half): [128 rows][8 slots of 16B], phys slot = logical ^ (row&7)  (bank floor).
// global_load_lds dest is linear; the XOR swizzle is applied on the GLOBAL source address instead.
// Schedule per iteration (tiles kt=it [buf0], it+1 [buf1]); stage events = 4 GLL (both halves):
//   P0: dsA(mh0,kk0)+dsB(kk0) | stage A(it+1)->buf1 | bar lgkm0 prio MFMA prio bar
//   P1: dsA(mh1,kk0)                                 | ...
//   P2: dsA(mh0,kk1)+dsB(kk1)                        | ...
//   P3: dsA(mh1,kk1) | stage B(it+2)->buf0 | ... MFMA ... vmcnt(4|0) bar   <- it+1 fully landed
//   P4..P7 mirror on buf1; P4 stages A(it+2)->buf0; P7 stages B(it+3)->buf1, vmcnt(4)
// Slot-reuse is race-free: a slot is only restaged in a phase strictly after its last ds_read phase.
template <int GH, int LGR>
__global__ __launch_bounds__(512, 2) void gemm256(
    const bf* __restrict__ A, const bf* __restrict__ W,
    const float* __restrict__ bias, bf* __restrict__ C,
    int M, int N, int K)
{
    extern __shared__ __attribute__((aligned(16))) char smem[];
    char* Asm = smem;                // [2 buf][2 half][16384 B]
    char* Bsm = smem + 65536;

    const int tid = threadIdx.x;
    const int lane = tid & 63;
    const int lm = lane & 15;
    const int quad = lane >> 4;
    const int wave = tid >> 6;
    const int wm = wave >> 2;        // 0..1  (A half)
    const int wn = wave & 3;         // 0..3
    const int row0 = blockIdx.x * 256, col0 = blockIdx.y * 256;
    const int NT = K >> 6;           // K multiple of 128

    // staging constants: thread t covers row (t>>3), phys slot (t&7); source slot pre-swizzled
    const int trow = tid >> 3;
    const int tslot = (tid & 7) ^ (trow & 7);
    const bf* Ath = A + (size_t)(row0 + trow) * K + tslot * 8;
    const bf* Wth = W + (size_t)(col0 + trow) * K + tslot * 8;

    // compute-side read bases + swizzled k-slot offsets
    const char* aBase = Asm + wm * 16384 + lm * 128;
    const char* bBase = Bsm + (wn >> 1) * 16384 + ((wn & 1) * 64 + lm) * 128;
    const int skz0 = ((quad ^ (lm & 7)) << 4);
    const int skz1 = (((4 + quad) ^ (lm & 7)) << 4);

    f32x4 acc[8][4] = {};

    auto stA = [&](int kt) {
        const int bo = (kt & 1) * 32768;
#pragma unroll
        for (int h = 0; h < 2; ++h)
#pragma unroll
            for (int s = 0; s < 2; ++s)
                GLL16(Ath + (size_t)(h * 128 + s * 64) * K + kt * 64,
                      Asm + bo + h * 16384 + s * 8192 + tid * 16);
    };
    auto stB = [&](int kt) {
        const int bo = (kt & 1) * 32768;
#pragma unroll
        for (int h = 0; h < 2; ++h)
#pragma unroll
            for (int s = 0; s < 2; ++s)
                GLL16(Wth + (size_t)(h * 128 + s * 64) * K + kt * 64,
                      Bsm + bo + h * 16384 + s * 8192 + tid * 16);
    };

#define LOADA(bo, mh, kk)                                                     \
    _Pragma("unroll")                                                         \
    for (int mm = 0; mm < 4; ++mm)                                            \
        a[mm] = *(const bf16x8*)(aBase + (bo) + ((mh) * 4 + mm) * 2048        \
                                 + ((kk) ? skz1 : skz0));
#define LOADB(bo, kk)                                                         \
    _Pragma("unroll")                                                         \
    for (int j = 0; j < 4; ++j)                                               \
        b[j] = *(const bf16x8*)(bBase + (bo) + j * 2048                       \
                                + ((kk) ? skz1 : skz0));
#define PH_OPEN()                                                             \
    __builtin_amdgcn_s_barrier();                                             \
    asm volatile("s_waitcnt lgkmcnt(0)" ::: "memory");                        \
    __builtin_amdgcn_s_setprio(1)
#define MM16(mh)                                                              \
    _Pragma("unroll")                                                         \
    for (int mm = 0; mm < 4; ++mm)                                            \
        _Pragma("unroll")                                                     \
        for (int j = 0; j < 4; ++j)                                           \
            acc[(mh) * 4 + mm][j] = MFMA(a[mm], b[j], acc[(mh) * 4 + mm][j]);
#define PH_CLOSE()                                                            \
    __builtin_amdgcn_s_setprio(0);                                            \
    __builtin_amdgcn_s_barrier()

    // prologue: stage B0, A0, B1; wait for tile0 (B1 may stay in flight)
    stB(0); stA(0); stB(1);
    asm volatile("s_waitcnt vmcnt(4)" ::: "memory");
    __builtin_amdgcn_s_barrier();

    for (int it = 0; it < NT; it += 2) {
        const int more = (it + 2 < NT);
        bf16x8 a[4], b[4];

        // ---- tile it (buf0) ----
        LOADA(0, 0, 0) LOADB(0, 0) stA(it + 1);
        PH_OPEN(); MM16(0) PH_CLOSE();

        LOADA(0, 1, 0)
        PH_OPEN(); MM16(1) PH_CLOSE();

        LOADA(0, 0, 1) LOADB(0, 1)
        PH_OPEN(); MM16(0) PH_CLOSE();

        LOADA(0, 1, 1) if (more) stB(it + 2);
        PH_OPEN(); MM16(1)
        __builtin_amdgcn_s_setprio(0);
        if (more) { asm volatile("s_waitcnt vmcnt(4)" ::: "memory"); }
        else      { asm volatile("s_waitcnt vmcnt(0)" ::: "memory"); }
        __builtin_amdgcn_s_barrier();

        // ---- tile it+1 (buf1) ----
        LOADA(32768, 0, 0) LOADB(32768, 0) if (more) stA(it + 2);
        PH_OPEN(); MM16(0) PH_CLOSE();

        LOADA(32768, 1, 0)
        PH_OPEN(); MM16(1) PH_CLOSE();

        LOADA(32768, 0, 1) LOADB(32768, 1)
        PH_OPEN(); MM16(0) PH_CLOSE();

        LOADA(32768, 1, 1) if (more) stB(it + 3);
        PH_OPEN(); MM16(1)
        __builtin_amdgcn_s_setprio(0);
        if (more) { asm volatile("s_waitcnt vmcnt(4)" ::: "memory"); }
        __builtin_amdgcn_s_barrier();
    }
#undef LOADA
#undef LOADB
#undef PH_OPEN
#undef MM16
#undef PH_CLOSE

    // ---- epilogue: bias + L2-norm per 64-col head, head-major bf16 out ----
    float bv[4];
#pragma unroll
    for (int j = 0; j < 4; ++j) bv[j] = bias[col0 + wn * 64 + j * 16 + lm];
    const int g = (col0 + wn * 64) >> 6;
#pragma unroll
    for (int m = 0; m < 8; ++m) {
#pragma unroll
        for (int rg = 0; rg < 4; ++rg) {
            float v[4];
            float ss = 0.f;
#pragma unroll
            for (int j = 0; j < 4; ++j) {
                const float x = acc[m][j][rg] + bv[j];
                v[j] = x;
                ss += x * x;
            }
            ss += __shfl_xor(ss, 1, 64);
            ss += __shfl_xor(ss, 2, 64);
            ss += __shfl_xor(ss, 4, 64);
            ss += __shfl_xor(ss, 8, 64);
            const float inv = 1.0f / fmaxf(sqrtf(ss), 1e-12f);
            const int row = row0 + wm * 128 + m * 16 + quad * 4 + rg;
            const int bt = row >> LGR;
            const int rl = row & ((1 << LGR) - 1);
            bf* Cr = C + (((size_t)(bt * GH + g) << LGR) + rl) * 64;
#pragma unroll
            for (int j = 0; j < 4; ++j)
                Cr[j * 16 + lm] = (bf)(v[j] * inv);
        }
    }
}

// ---------------- flash-style cosine attention, NO-MAX softmax (unchanged) ----------------
__global__ __launch_bounds__(256, 4) void attn(
    const bf* __restrict__ qn, const bf* __restrict__ kvn, bf* __restrict__ X)
{
    __shared__ __attribute__((aligned(16))) bf Kt[128 * 72];
    __shared__ __attribute__((aligned(16))) bf Vt[64 * 136];
    __shared__ __attribute__((aligned(16))) bf Ps[4][16 * 40];

    const int qb = blockIdx.x >> 9;
    const int rb = blockIdx.x & 511;
    const int bt = rb >> 3;
    const int h = rb & 7;
    const int tid = threadIdx.x;
    const int lane = tid & 63;
    const int wave = tid >> 6;
    const int lm = lane & 15;
    const int quad = lane >> 4;

    const bf* qh = qn + ((size_t)(bt * 8 + h) * 256 + qb * 128) * 64;
    const bf* kh = kvn + (size_t)(bt * 16 + h) * 512 * 64;
    const bf* vh = kvn + (size_t)(bt * 16 + 8 + h) * 512 * 64;

    const int srow = tid >> 1;
    const int sseg = (tid & 1) * 32;

    f32x4 o[2][4] = {};
    float sum[2][4] = {};
    bf* Pw = &Ps[wave][0];

    for (int t = 0; t < 4; ++t) {
        {
            const bf* kr = kh + (size_t)(t * 128 + srow) * 64 + sseg;
            bf* kd = Kt + srow * 72 + sseg;
#pragma unroll
            for (int j = 0; j < 4; ++j)
                *(bf16x8*)(kd + j * 8) = *(const bf16x8*)(kr + j * 8);

            const bf* vr = vh + (size_t)(t * 128 + srow) * 64 + sseg;
            bf16x8 vv[4];
#pragma unroll
            for (int j = 0; j < 4; ++j) vv[j] = *(const bf16x8*)(vr + j * 8);
#pragma unroll
            for (int j = 0; j < 4; ++j)
#pragma unroll
                for (int e = 0; e < 8; ++e)
                    Vt[(sseg + j * 8 + e) * 136 + srow] = vv[j][e];
        }
        __syncthreads();

#pragma unroll
        for (int c = 0; c < 2; ++c) {
            const int r0 = wave * 32 + c * 16;
            const bf* qp = qh + (size_t)(r0 + lm) * 64 + quad * 8;
            const bf16x8 a0 = *(const bf16x8*)qp;
            const bf16x8 a1 = *(const bf16x8*)(qp + 32);

            f32x4 s[8];
#pragma unroll
            for (int nt = 0; nt < 8; ++nt) {
                const bf16x8 k0 = *(const bf16x8*)(&Kt[(nt * 16 + lm) * 72 + quad * 8]);
                const bf16x8 k1 = *(const bf16x8*)(&Kt[(nt * 16 + lm) * 72 + 32 + quad * 8]);
                f32x4 z = {};
                z = MFMA(a0, k0, z);
                s[nt] = MFMA(a1, k1, z);
            }

            for (int ntp = 0; ntp < 4; ++ntp) {
#pragma unroll
                for (int tt = 0; tt < 2; ++tt)
#pragma unroll
                    for (int rr = 0; rr < 4; ++rr) {
                        const float e = __expf(s[ntp * 2 + tt][rr] * 0.125f);
                        sum[c][rr] += e;
                        Pw[(quad * 4 + rr) * 40 + tt * 16 + lm] = (bf)e;
                    }
                const bf16x8 ap = *(const bf16x8*)(&Pw[lm * 40 + quad * 8]);
#pragma unroll
                for (int dt = 0; dt < 4; ++dt) {
                    const bf16x8 bv = *(const bf16x8*)(&Vt[(dt * 16 + lm) * 136 + ntp * 32 + quad * 8]);
                    o[c][dt] = MFMA(ap, bv, o[c][dt]);
                }
            }
        }
        __syncthreads();
    }

#pragma unroll
    for (int c = 0; c < 2; ++c) {
        float inv[4];
#pragma unroll
        for (int rr = 0; rr < 4; ++rr) {
            float sm = sum[c][rr];
            sm += __shfl_xor(sm, 1, 64);
            sm += __shfl_xor(sm, 2, 64);
            sm += __shfl_xor(sm, 4, 64);
            sm += __shfl_xor(sm, 8, 64);
            inv[rr] = 1.0f / sm;
        }
        bf* Xp = X + ((size_t)bt * 256 + qb * 128 + wave * 32 + c * 16) * 512 + h * 64;
#pragma unroll
        for (int dt = 0; dt < 4; ++dt)
#pragma unroll
            for (int rr = 0; rr < 4; ++rr)
                Xp[(size_t)(quad * 4 + rr) * 512 + dt * 16 + lm] = (bf)(o[c][dt][rr] * inv[rr]);
    }
}

extern "C" void kernel_launch(void* const* d_in, const int* in_sizes, int n_in,
                              void* d_out, int out_size, void* d_ws, size_t ws_size,
                              hipStream_t stream)
{
    const float* q   = (const float*)d_in[0];
    const float* kv  = (const float*)d_in[1];
    const float* Wq  = (const float*)d_in[2];
    const float* bq  = (const float*)d_in[3];
    const float* Wkv = (const float*)d_in[4];
    const float* bkv = (const float*)d_in[5];
    const float* Wm  = (const float*)d_in[6];
    const float* bm  = (const float*)d_in[7];
    float* out = (float*)d_out;

    char* ws = (char*)d_ws;
    bf* kvb = (bf*)ws;                          // [0,32 MiB)  kv bf16 (dead after KV-proj)
    bf* kvn = (bf*)(ws + (size_t)(32 << 20));   // [32,96 MiB) normalized kv heads (head-major)
    bf* wqb = (bf*)ws;                          // [0,0.5 MiB) Wq bf16 (after kvb dead)
    bf* wmb = (bf*)(ws + (size_t)(16 << 20));   // [16,16.5 MiB) Wm bf16 (after kvb dead)
    bf* X   = (bf*)ws;                          // [0,16 MiB)  attn output (after wqb dead)
    char* dob = (char*)d_out;
    bf* wkvb = (bf*)dob;                        // d_out[0,1 MiB) Wkv bf16 (dead after KV-proj)
    bf* qb   = (bf*)dob;                        // d_out[0,16 MiB) q bf16 (overwrites wkvb)
    bf* qn   = (bf*)(dob + (size_t)(16 << 20)); // d_out[16,32 MiB) normalized q heads (head-major)

    // allow 128 KiB dynamic LDS for the 8-phase GEMMs (immediate, not a stream op)
    {
        auto k0 = gemm256<16, 9>;
        auto k1 = gemm256<8, 8>;
        (void)hipFuncSetAttribute((const void*)k0, hipFuncAttributeMaxDynamicSharedMemorySize, 131072);
        (void)hipFuncSetAttribute((const void*)k1, hipFuncAttributeMaxDynamicSharedMemorySize, 131072);
    }

    // 1. kv + Wkv -> bf16
    cvt2<<<dim3(8448), 256, 0, stream>>>(kv, kvb, 2097152, Wkv, wkvb, 65536);
    // 2. KV projection + bias + fused L2-norm -> head-major kvn (bt,16,512,64)  [8-phase 256^2]
    gemm256<16, 9><<<dim3(128, 4), 512, 131072, stream>>>(kvb, wkvb, bkv, kvn, 32768, 1024, 512);
    // 3. q, Wq, Wm -> bf16
    cvt3<<<dim3(4352), 256, 0, stream>>>(q, qb, 1048576, Wq, wqb, 32768, Wm, wmb, 32768);
    // 4. Q projection + bias + fused L2-norm -> head-major qn (bt,8,256,64)  [8-phase 256^2]
    gemm256<8, 8><<<dim3(64, 2), 512, 131072, stream>>>(qb, wqb, bq, qn, 16384, 512, 512);
    // 5. no-max flash cosine attention
    attn<<<dim3(1024), 256, 0, stream>>>(qn, kvn, X);
    // 6. output projection + bias + fp32 residual -> fp32 out
    gemm128<1, 0, 0><<<dim3(128, 4), 256, 0, stream>>>(X, wmb, bm, q, out, 16384, 512, 512);
}